// Round 8
// baseline (194.894 us; speedup 1.0000x reference)
//
#include <hip/hip_runtime.h>

#define N_NODES 50000
#define N_EDGES 800000
#define D 128
#define HP 128              // histogram / fill partition blocks
#define EPB (N_EDGES / HP)  // 6250 edges per partition
#define NW (N_NODES / 2)    // 25000 packed u32 words (2 nodes/word)
#define NWB 98              // ceil(NW/256) reduce/scan blocks (512 nodes each)
#define GNB 1563            // ceil(N_NODES/32) gather blocks per feature pass
#define PSB 3125            // prescale blocks (N*16/256)

typedef __attribute__((ext_vector_type(8))) short short8;   // 8 bf16
typedef __attribute__((ext_vector_type(4))) float f32x4;

__device__ __forceinline__ unsigned short f2bf(float f) {
    unsigned u = __float_as_uint(f);
    return (unsigned short)((u + 0x7FFFu + ((u >> 16) & 1u)) >> 16);  // RNE
}
__device__ __forceinline__ float bf2f(unsigned short h) {
    return __uint_as_float((unsigned)h << 16);
}

// ---- degrees via per-block LDS histograms (no global atomics) ----
// LDS word w packs: in[2w](b0) | out[2w](b1) | in[2w+1](b2) | out[2w+1](b3), u8 each.
__global__ __launch_bounds__(256) void k_hist(const int2* __restrict__ el2,
                                              unsigned int* __restrict__ partials) {
    __shared__ unsigned int h[NW];  // 100 KB
    int t = threadIdx.x;
    for (int i = t; i < NW / 4; i += 256) ((uint4*)h)[i] = make_uint4(0, 0, 0, 0);
    __syncthreads();
    const int2* p = el2 + blockIdx.x * EPB;
    for (int i = t; i < EPB; i += 256) {
        int2 st = p[i];
        atomicAdd(&h[st.x >> 1], 1u << ((st.x & 1) * 16));       // in-degree byte
        atomicAdd(&h[st.y >> 1], 256u << ((st.y & 1) * 16));     // out-degree byte
    }
    __syncthreads();
    uint4* dst = (uint4*)(partials + (size_t)blockIdx.x * NW);
    for (int i = t; i < NW / 4; i += 256) dst[i] = ((uint4*)h)[i];
}

// ---- fused: degree totals + cross-block exclusive prefixes (brel) + 512-node
// block sums. so = sum of (v>>8)&0x00FF00FF -> out[2w] in so[15:0],
// out[2w+1] in so[31:16] (counts <= ~60; high bytes stay 0). ----
__global__ __launch_bounds__(256) void k_reduce(const unsigned int* __restrict__ partials,
                                                unsigned char* __restrict__ brel,
                                                int* __restrict__ deg_in,
                                                int* __restrict__ deg_out,
                                                int* __restrict__ blk_sum) {
    __shared__ int sc[256];
    int t = threadIdx.x;
    int w = blockIdx.x * 256 + t;
    unsigned int si = 0, so = 0;
    if (w < NW) {
        for (int p = 0; p < HP; ++p) {
            unsigned pre = (so & 0xFFu) | (((so >> 16) & 0xFFu) << 8);
            ((unsigned short*)(brel + (size_t)p * N_NODES))[w] = (unsigned short)pre;
            unsigned int v = partials[p * NW + w];
            si += v & 0x00FF00FFu;
            so += (v >> 8) & 0x00FF00FFu;
        }
        *(int2*)&deg_in[2 * w]  = make_int2(si & 0xFFFF, si >> 16);
        *(int2*)&deg_out[2 * w] = make_int2(so & 0xFFFF, so >> 16);
    }
    sc[t] = (w < NW) ? (int)((so & 0xFFFFu) + (so >> 16)) : 0;
    __syncthreads();
    for (int s = 128; s > 0; s >>= 1) {
        if (t < s) sc[t] += sc[t + s];
        __syncthreads();
    }
    if (t == 0) blk_sum[blockIdx.x] = sc[0];
}

// ---- fused mid-phase: blocks 0..NWB-1 -> row_start (inline exclusive scan of
// blk_sum, no separate scan_b dispatch); blocks NWB.. -> prescale xst. ----
__global__ __launch_bounds__(256) void k_mid(const int* __restrict__ deg_out,
                                             const int* __restrict__ blk_sum,
                                             int* __restrict__ row_start,
                                             const float4* __restrict__ x4,
                                             const int* __restrict__ deg_in,
                                             uint4* __restrict__ xst) {
    if (blockIdx.x < NWB) {
        __shared__ int sc[256];
        __shared__ int pref;
        int t = threadIdx.x;
        // prefix of preceding block sums (NWB=98 <= 256 threads)
        sc[t] = (t < (int)blockIdx.x) ? blk_sum[t] : 0;
        __syncthreads();
        for (int s = 128; s > 0; s >>= 1) {
            if (t < s) sc[t] += sc[t + s];
            __syncthreads();
        }
        if (t == 0) pref = sc[0];
        __syncthreads();
        int blkoff = pref;
        int w = blockIdx.x * 256 + t;
        int v0 = 0, v1 = 0;
        if (w < NW) { int2 d2 = *(const int2*)&deg_out[2 * w]; v0 = d2.x; v1 = d2.y; }
        int pair = v0 + v1;
        __syncthreads();
        sc[t] = pair;
        __syncthreads();
        for (int off = 1; off < 256; off <<= 1) {
            int a = (t >= off) ? sc[t - off] : 0;
            __syncthreads();
            sc[t] += a;
            __syncthreads();
        }
        if (w < NW) {
            int base = blkoff + sc[t] - pair;
            *(int2*)&row_start[2 * w] = make_int2(base, base + v0);
        }
    } else {
        // prescale: xst[f][n][32] = bf16(rsqrt(deg_in[n]+1) * x[n][f*32..+32])
        int g = (blockIdx.x - NWB) * 256 + threadIdx.x;  // PSB*256 = N*16 exact
        int n = g >> 4, part = g & 15;
        int f = part >> 2, off = part & 3;
        float rs = rsqrtf((float)(deg_in[n] + 1));
        float4 a = x4[g * 2], c = x4[g * 2 + 1];
        uint4 o;
        o.x = f2bf(rs * a.x) | ((unsigned)f2bf(rs * a.y) << 16);
        o.y = f2bf(rs * a.z) | ((unsigned)f2bf(rs * a.w) << 16);
        o.z = f2bf(rs * c.x) | ((unsigned)f2bf(rs * c.y) << 16);
        o.w = f2bf(rs * c.z) | ((unsigned)f2bf(rs * c.w) << 16);
        xst[(size_t)f * N_NODES * 4 + n * 4 + off] = o;  // uint4 units (8 bf16)
    }
}

// ---- counting-sort placement, NO global atomics; srcs stored as u16 ----
__global__ __launch_bounds__(256) void k_fill(const int2* __restrict__ el2,
                                              const int* __restrict__ row_start,
                                              const unsigned char* __restrict__ brel,
                                              unsigned short* __restrict__ srcs) {
    __shared__ unsigned int cur[NW];  // 100 KB packed u16 cursors
    int t = threadIdx.x;
    for (int i = t; i < NW / 4; i += 256) ((uint4*)cur)[i] = make_uint4(0, 0, 0, 0);
    __syncthreads();
    const int2* p = el2 + blockIdx.x * EPB;
    const unsigned char* br = brel + (size_t)blockIdx.x * N_NODES;
    for (int i = t; i < EPB; i += 256) {
        int2 st = p[i];
        int n = st.y;
        unsigned old = atomicAdd(&cur[n >> 1], 1u << ((n & 1) * 16));
        int rank = (old >> ((n & 1) * 16)) & 0xFFFF;
        srcs[row_start[n] + (int)br[n] + rank] = (unsigned short)st.x;
    }
}

// ---- gather, one feature pass per launch: reads only xst[pass] (3.2MB,
// fits per-XCD L2; launches serialize -> one tile hot at a time).
// 8 lanes/node; 1 u16 index load per 8 edges per lane + __shfl broadcast. ----
__global__ __launch_bounds__(256) void k_gather(const unsigned short* __restrict__ xst,
                                                const unsigned short* __restrict__ srcs,
                                                const int* __restrict__ row_start,
                                                const int* __restrict__ deg_out,
                                                unsigned short* __restrict__ ut,
                                                int pass) {
    int n = blockIdx.x * 32 + (threadIdx.x >> 3);
    if (n >= N_NODES) return;
    int d = threadIdx.x & 7;
    int lane = threadIdx.x & 63;
    int lbase = lane & ~7;  // 8-lane group base within wave
    const unsigned short* xb = xst + (size_t)pass * N_NODES * 32;
    int cnt = deg_out[n];
    float rd = rsqrtf((float)(cnt + 1));
    ushort4 sv = *(const ushort4*)&xb[n * 32 + d * 4];  // self (rs-scaled)
    float a0 = bf2f(sv.x), a1 = bf2f(sv.y), a2 = bf2f(sv.z), a3 = bf2f(sv.w);
    const unsigned short* p = srcs + row_start[n];
    int k = 0;
    for (; k + 8 <= cnt; k += 8) {
        int myidx = (int)p[k + d];  // 8 lanes load 8 consecutive u16 = 16B/group
        ushort4 v[8];
        #pragma unroll
        for (int j = 0; j < 8; ++j) {
            int s = __shfl(myidx, lbase + j, 64);
            v[j] = *(const ushort4*)&xb[s * 32 + d * 4];
        }
        #pragma unroll
        for (int j = 0; j < 8; ++j) {
            a0 += bf2f(v[j].x); a1 += bf2f(v[j].y);
            a2 += bf2f(v[j].z); a3 += bf2f(v[j].w);
        }
    }
    for (; k < cnt; ++k) {
        ushort4 vv = *(const ushort4*)&xb[(int)p[k] * 32 + d * 4];
        a0 += bf2f(vv.x); a1 += bf2f(vv.y); a2 += bf2f(vv.z); a3 += bf2f(vv.w);
    }
    ushort4 o;
    o.x = f2bf(rd * a0); o.y = f2bf(rd * a1); o.z = f2bf(rd * a2); o.w = f2bf(rd * a3);
    *(ushort4*)&ut[(size_t)pass * N_NODES * 32 + n * 32 + d * 4] = o;
}

// ---- combine: out = relu(u @ W^T + b) via bf16 MFMA; u is feature-tiled ----
__global__ __launch_bounds__(256) void k_gemm(const float* __restrict__ W,
                                              const float* __restrict__ bias,
                                              const unsigned short* __restrict__ ut,
                                              float* __restrict__ out) {
    __shared__ unsigned short Wl[128 * 136];
    const int tid = threadIdx.x;
    for (int i = tid; i < 128 * 32; i += 256) {
        int r = i >> 5, c = i & 31;
        float4 w4 = *(const float4*)&W[r * D + c * 4];
        ushort4 hh;
        hh.x = f2bf(w4.x); hh.y = f2bf(w4.y); hh.z = f2bf(w4.z); hh.w = f2bf(w4.w);
        *(ushort4*)&Wl[r * 136 + c * 4] = hh;
    }
    __syncthreads();

    const int wv = tid >> 6, lane = tid & 63, ml = lane & 15, q = lane >> 4;
    const int nchunks = (N_NODES + 63) / 64;

    for (int chunk = blockIdx.x; chunk < nchunks; chunk += gridDim.x) {
        int base = chunk * 64;
        int arow = base + wv * 16 + ml;

        short8 a[4];
        if (arow < N_NODES) {
            #pragma unroll
            for (int kt = 0; kt < 4; ++kt)   // k-chunk kt lives in tile kt
                a[kt] = *(const short8*)&ut[(size_t)kt * N_NODES * 32 + arow * 32 + q * 8];
        } else {
            #pragma unroll
            for (int kt = 0; kt < 4; ++kt) a[kt] = (short8){0, 0, 0, 0, 0, 0, 0, 0};
        }

        f32x4 acc[8];
        #pragma unroll
        for (int jj = 0; jj < 8; ++jj) acc[jj] = (f32x4){0.f, 0.f, 0.f, 0.f};

        #pragma unroll
        for (int jj = 0; jj < 8; ++jj) {
            #pragma unroll
            for (int kt = 0; kt < 4; ++kt) {
                short8 bw = *(const short8*)&Wl[(jj * 16 + ml) * 136 + kt * 32 + q * 8];
                acc[jj] = __builtin_amdgcn_mfma_f32_16x16x32_bf16(a[kt], bw, acc[jj], 0, 0, 0);
            }
        }

        #pragma unroll
        for (int jj = 0; jj < 8; ++jj) {
            float bj = bias[jj * 16 + ml];
            #pragma unroll
            for (int r4 = 0; r4 < 4; ++r4) {
                int node = base + wv * 16 + q * 4 + r4;
                if (node < N_NODES) {
                    float v = acc[jj][r4] + bj;
                    out[node * D + jj * 16 + ml] = v > 0.f ? v : 0.f;
                }
            }
        }
    }
}

extern "C" void kernel_launch(void* const* d_in, const int* in_sizes, int n_in,
                              void* d_out, int out_size, void* d_ws, size_t ws_size,
                              hipStream_t stream) {
    const int*   el = (const int*)d_in[0];
    const float* x  = (const float*)d_in[1];
    const float* W  = (const float*)d_in[2];
    const float* b  = (const float*)d_in[3];
    float* out = (float*)d_out;

    // workspace layout (4B words); brel aliases ut (disjoint lifetimes:
    // brel written by k_reduce, read by k_fill; ut written by k_gather AFTER fill).
    unsigned int* partials = (unsigned int*)d_ws;                           // HP*NW = 3.2M
    unsigned short* xst    = (unsigned short*)(partials + (size_t)HP * NW); // N*128 bf16
    unsigned short* ut     = xst + (size_t)N_NODES * D;                     // N*128 bf16
    unsigned char* brel    = (unsigned char*)ut;                            // HP*N u8 (alias)
    unsigned short* srcs   = ut + (size_t)N_NODES * D;                      // E u16
    int* deg_in    = (int*)(srcs + N_EDGES);                                // N
    int* deg_out   = deg_in + N_NODES;                                      // N
    int* row_start = deg_out + N_NODES;                                     // N
    int* blk_sum   = row_start + N_NODES;                                   // NWB
    // total ~ 40 MB

    k_hist<<<HP, 256, 0, stream>>>((const int2*)el, partials);
    k_reduce<<<NWB, 256, 0, stream>>>(partials, brel, deg_in, deg_out, blk_sum);
    k_mid<<<NWB + PSB, 256, 0, stream>>>(deg_out, blk_sum, row_start,
                                         (const float4*)x, deg_in, (uint4*)xst);
    k_fill<<<HP, 256, 0, stream>>>((const int2*)el, row_start, brel, srcs);
    for (int pass = 0; pass < 4; ++pass)
        k_gather<<<GNB, 256, 0, stream>>>(xst, srcs, row_start, deg_out, ut, pass);
    k_gemm<<<256, 256, 0, stream>>>(W, b, ut, out);
}